// Round 3
// baseline (38.608 us; speedup 1.0000x reference)
//
#include <hip/hip_runtime.h>
#include <hip/hip_bf16.h>

#define D 64      // hidden dim
#define D2 128    // ff inner dim
#define NV 64     // vocab size
#define NT 4      // num query types
#define NB 256    // batch
#define LL 4096   // seq len
#define KK 8      // memory slots

// ---------------------------------------------------------------------------
// Single fused kernel. grid = NB(256) blocks x 256 threads, 1 block per CU.
// Blocks 0..63 are ALSO producers: block b computes H[b] (=LN(e+FFN(e))) and
// gH[b] (=H[b].gate_w[:64]), publishes to workspace, bumps a device-scope
// flag. Every block (producer or not) does its batch row's histogram and
// weight staging concurrently, then waits for flag==64 before the
// table-dependent finalize. All 256 blocks are co-resident (1 per CU,
// capacity >=2 per CU), so the spin cannot deadlock.
// ---------------------------------------------------------------------------
__global__ void __launch_bounds__(256) fused_kernel(
    const int*   __restrict__ seq,
    const float* __restrict__ embed,
    const float* __restrict__ ff1_w, const float* __restrict__ ff1_b,
    const float* __restrict__ ff2_w, const float* __restrict__ ff2_b,
    const float* __restrict__ ln_g,  const float* __restrict__ ln_b,
    const float* __restrict__ gate_w,
    const float* __restrict__ q_w,   const float* __restrict__ q_b,
    const float* __restrict__ tp_w,  const float* __restrict__ tp_b,
    const float* __restrict__ out_w, const float* __restrict__ out_b,
    int*   __restrict__ flag,
    float* __restrict__ Hg, float* __restrict__ gHg,
    float* __restrict__ out)   // logits [0,NB*D), type_dist [NB*D, NB*D+NB*NT)
{
    __shared__ float sH[NV * D];     // 16 KB H table
    __shared__ float sW[NV * D];     // 16 KB out_w
    __shared__ float sQw[NV * D];    // 16 KB q_w
    __shared__ float sP[256];
    __shared__ float sF[D2];
    __shared__ float sE[D];
    __shared__ float stp[D * NT];
    __shared__ float sgv[NV];
    __shared__ float smean[D];
    __shared__ float soub[D];
    __shared__ float sqb[D];
    __shared__ float sq[D];
    __shared__ float sread[D];
    __shared__ float stpb[NT];
    __shared__ float std4[NT];
    __shared__ int   cnt[NV];
    __shared__ int   order[NV];
    __shared__ int   selv[KK], selc[KK];
    __shared__ float selw[KK], ssc[KK];
    __shared__ int   snsel, slastS;

    const int b = blockIdx.x;
    const int tid = threadIdx.x;

    // ---- issue ALL independent global loads up front ------------------------
    const int4* s4 = reinterpret_cast<const int4*>(seq + (size_t)b * LL);
    const int4 x0 = s4[tid];
    const int4 x1 = s4[256 + tid];
    const int4 x2 = s4[512 + tid];
    const int4 x3 = s4[768 + tid];
    {
        const float4* w4 = reinterpret_cast<const float4*>(out_w);
        const float4* q4 = reinterpret_cast<const float4*>(q_w);
        float4* sw4 = reinterpret_cast<float4*>(sW);
        float4* sq4 = reinterpret_cast<float4*>(sQw);
        #pragma unroll
        for (int k = 0; k < 4; ++k) sw4[k*256 + tid] = w4[k*256 + tid];
        #pragma unroll
        for (int k = 0; k < 4; ++k) sq4[k*256 + tid] = q4[k*256 + tid];
    }
    stp[tid] = tp_w[tid];                               // D*NT == 256 exactly
    if (tid < NV) { cnt[tid] = 0; soub[tid] = out_b[tid]; sqb[tid] = q_b[tid]; }
    if (tid < NT) stpb[tid] = tp_b[tid];

    if (b < NV) {
        // ================= producer: H[b], gH[b] =============================
        if (tid < D) sE[tid] = embed[b*D + tid];
        __syncthreads();
        {   // ff1 partials: output o = tid&127, half covers 32 of 64 i's
            const int o = tid & (D2-1), half = tid >> 7;
            float acc = 0.0f;
            #pragma unroll
            for (int k = 0; k < 32; ++k) {
                const int i = half*32 + k;
                acc = fmaf(sE[i], ff1_w[i*D2 + o], acc);
            }
            sP[tid] = acc;
        }
        __syncthreads();
        if (tid < D2) sF[tid] = fmaxf(sP[tid] + sP[tid+128] + ff1_b[tid], 0.0f);
        __syncthreads();
        {   // ff2 partials: output o = tid&63, quarter covers 32 of 128 j's
            const int o = tid & 63, qq = tid >> 6;
            float acc = 0.0f;
            #pragma unroll
            for (int k = 0; k < 32; ++k) {
                const int j = qq*32 + k;
                acc = fmaf(sF[j], ff2_w[j*D + o], acc);
            }
            sP[tid] = acc;
        }
        __syncthreads();
        if (tid < D) {   // residual + LayerNorm on wave 0
            float x = sE[tid] + sP[tid] + sP[tid+64] + sP[tid+128] + sP[tid+192]
                    + ff2_b[tid];
            float s = x;
            #pragma unroll
            for (int off = 32; off >= 1; off >>= 1) s += __shfl_xor(s, off, 64);
            const float mu = s * (1.0f / D);
            const float t  = x - mu;
            float vs = t * t;
            #pragma unroll
            for (int off = 32; off >= 1; off >>= 1) vs += __shfl_xor(vs, off, 64);
            const float rs = rsqrtf(vs * (1.0f / D) + 1e-5f);
            const float h  = t * rs * ln_g[tid] + ln_b[tid];
            Hg[b*D + tid] = h;
            float g = h * gate_w[tid];
            #pragma unroll
            for (int off = 32; off >= 1; off >>= 1) g += __shfl_xor(g, off, 64);
            if (tid == 0) gHg[b] = g;
        }
        __syncthreads();              // drains vmcnt: H/gH stores are complete
        if (tid == 0) { __threadfence(); atomicAdd(flag, 1); }  // release+publish
    } else {
        __syncthreads();              // cover cnt zeroing before atomics
    }

    // ---- histogram (overlaps with producers' compute on other CUs) ----------
    atomicAdd(&cnt[x0.x], 1); atomicAdd(&cnt[x0.y], 1);
    atomicAdd(&cnt[x0.z], 1); atomicAdd(&cnt[x0.w], 1);
    atomicAdd(&cnt[x1.x], 1); atomicAdd(&cnt[x1.y], 1);
    atomicAdd(&cnt[x1.z], 1); atomicAdd(&cnt[x1.w], 1);
    atomicAdd(&cnt[x2.x], 1); atomicAdd(&cnt[x2.y], 1);
    atomicAdd(&cnt[x2.z], 1); atomicAdd(&cnt[x2.w], 1);
    atomicAdd(&cnt[x3.x], 1); atomicAdd(&cnt[x3.y], 1);
    atomicAdd(&cnt[x3.z], 1); atomicAdd(&cnt[x3.w], 1);
    if (tid == 255) slastS = x3.w;    // seq[b][4095], already in register
    __syncthreads();

    // ---- wait for the H/gH tables (acquire) ---------------------------------
    if (tid == 0) {
        while (__hip_atomic_load(flag, __ATOMIC_RELAXED,
                                 __HIP_MEMORY_SCOPE_AGENT) < NV) {}
    }
    __syncthreads();
    __threadfence();                  // acquire: invalidate L1 before table reads

    // ---- stage H table + gH -------------------------------------------------
    {
        const float4* h4 = reinterpret_cast<const float4*>(Hg);
        float4* sh4 = reinterpret_cast<float4*>(sH);
        #pragma unroll
        for (int k = 0; k < 4; ++k) sh4[k*256 + tid] = h4[k*256 + tid];
    }
    if (tid < NV) sgv[tid] = gHg[tid];
    __syncthreads();

    // ---- meanh[d] = sum_v cnt[v]*H[v][d] / L  (4-way split) -----------------
    {
        const int d = tid & 63, g = tid >> 6;
        float acc = 0.0f;
        #pragma unroll
        for (int k = 0; k < 16; ++k) {
            const int v = g*16 + k;
            acc = fmaf((float)cnt[v], sH[v*D + d], acc);
        }
        sP[tid] = acc;
    }
    __syncthreads();
    if (tid < D)
        smean[tid] = (sP[tid] + sP[tid+64] + sP[tid+128] + sP[tid+192]) * (1.0f / LL);
    __syncthreads();

    // ---- type logits: one wave per type ------------------------------------
    {
        const int t = tid >> 6, i = tid & 63;
        float val = smean[i] * stp[i*NT + t];
        #pragma unroll
        for (int off = 32; off >= 1; off >>= 1) val += __shfl_xor(val, off, 64);
        if (i == 0) std4[t] = val + stpb[t];
    }
    __syncthreads();
    if (tid < NT) {
        const float a0 = std4[0], a1 = std4[1], a2 = std4[2], a3 = std4[3];
        const float mx = fmaxf(fmaxf(a0, a1), fmaxf(a2, a3));
        const float den = expf(a0-mx) + expf(a1-mx) + expf(a2-mx) + expf(a3-mx);
        out[NB*D + b*NT + tid] = expf(std4[tid] - mx) / den;
    }

    // ---- rank present token values by (gH desc, id asc) ---------------------
    // sigmoid(gH + per-row-const) is strictly monotone in gH -> same top-k as
    // the reference; tpr/gate_b/sigmoid drop out. Same-id ties give identical
    // h rows; distinct-id exact-float ties are measure-zero.
    if (tid < NV && cnt[tid] > 0) {
        const float g = sgv[tid];
        int r = 0;
        for (int u = 0; u < NV; ++u) {
            if (cnt[u] > 0) {
                const float gu = sgv[u];
                if (gu > g || (gu == g && u < tid)) ++r;
            }
        }
        order[r] = tid;
    }
    __syncthreads();
    if (tid == 0) {   // top-8 multiset walk (<=8 steps)
        int taken = 0, idx = 0;
        while (taken < KK) {
            const int v = order[idx];
            int c = cnt[v]; if (c > KK - taken) c = KK - taken;
            selv[idx] = v; selc[idx] = c; taken += c; ++idx;
        }
        snsel = idx;
    }
    __syncthreads();

    // ---- q = H[slast] @ q_w + q_b  (4-way split) ----------------------------
    {
        const int o = tid & 63, g = tid >> 6;
        const int sl = slastS;
        float acc = 0.0f;
        #pragma unroll
        for (int k = 0; k < 16; ++k) {
            const int i = g*16 + k;
            acc = fmaf(sH[sl*D + i], sQw[i*D + o], acc);
        }
        sP[tid] = acc;
    }
    __syncthreads();
    if (tid < D)
        sq[tid] = sP[tid] + sP[tid+64] + sP[tid+128] + sP[tid+192] + sqb[tid];
    __syncthreads();

    // ---- attention scores: wave w handles slots w and w+4 -------------------
    {
        const int w = tid >> 6, i = tid & 63;
        const int n = snsel;
        #pragma unroll
        for (int s = 0; s < KK; s += 4) {
            const int slot = s + w;
            if (slot < n) {
                float val = sH[selv[slot]*D + i] * sq[i];
                #pragma unroll
                for (int off = 32; off >= 1; off >>= 1) val += __shfl_xor(val, off, 64);
                if (i == 0) ssc[slot] = val;
            }
        }
    }
    __syncthreads();
    if (tid == 0) {
        const int n = snsel;
        float mx = -1e30f;
        for (int i = 0; i < n; ++i) mx = fmaxf(mx, ssc[i]);
        float e[KK]; float den = 0.0f;
        for (int i = 0; i < n; ++i) { e[i] = (float)selc[i] * expf(ssc[i] - mx); den += e[i]; }
        const float inv = 1.0f / den;
        for (int i = 0; i < n; ++i) selw[i] = e[i] * inv;
    }
    __syncthreads();

    // ---- read vector --------------------------------------------------------
    if (tid < D) {
        float acc = 0.0f;
        const int n = snsel;
        for (int s = 0; s < n; ++s) acc = fmaf(selw[s], sH[selv[s]*D + tid], acc);
        sread[tid] = acc;
    }
    __syncthreads();

    // ---- logits = read @ out_w + out_b  (4-way split) -----------------------
    {
        const int d = tid & 63, g = tid >> 6;
        float acc = 0.0f;
        #pragma unroll
        for (int k = 0; k < 16; ++k) {
            const int i = g*16 + k;
            acc = fmaf(sread[i], sW[i*D + d], acc);
        }
        sP[tid] = acc;
    }
    __syncthreads();
    if (tid < D)
        out[(size_t)b*D + tid] = sP[tid] + sP[tid+64] + sP[tid+128] + sP[tid+192] + soub[tid];
}

// ---------------------------------------------------------------------------
extern "C" void kernel_launch(void* const* d_in, const int* in_sizes, int n_in,
                              void* d_out, int out_size, void* d_ws, size_t ws_size,
                              hipStream_t stream) {
    const int*   seq    = (const int*)  d_in[0];
    const float* embed  = (const float*)d_in[1];
    const float* ff1_w  = (const float*)d_in[2];
    const float* ff1_b  = (const float*)d_in[3];
    const float* ff2_w  = (const float*)d_in[4];
    const float* ff2_b  = (const float*)d_in[5];
    const float* ln_g   = (const float*)d_in[6];
    const float* ln_b   = (const float*)d_in[7];
    const float* tp_w   = (const float*)d_in[8];
    const float* tp_b   = (const float*)d_in[9];
    // d_in[10] tpr_w, d_in[11] tpr_b, d_in[13] gate_b: dead — they only add a
    // per-row constant to the pre-sigmoid gate, which cannot change top-k.
    const float* gate_w = (const float*)d_in[12];
    const float* q_w    = (const float*)d_in[14];
    const float* q_b    = (const float*)d_in[15];
    const float* out_w  = (const float*)d_in[16];
    const float* out_b  = (const float*)d_in[17];
    float* outp = (float*)d_out;

    // workspace layout: [flag int][pad to 64B][H: 4096 f][gH: 64 f]
    int*   flag = (int*)d_ws;
    float* Hg   = (float*)d_ws + 16;
    float* gHg  = Hg + NV*D;

    // deterministic flag reset each call (graph-capturable memset node);
    // makes the harness's one-time 0xAA workspace poison harmless.
    hipMemsetAsync(flag, 0, sizeof(int), stream);

    fused_kernel<<<NB, 256, 0, stream>>>(seq, embed, ff1_w, ff1_b, ff2_w, ff2_b,
                                         ln_g, ln_b, gate_w, q_w, q_b,
                                         tp_w, tp_b, out_w, out_b,
                                         flag, Hg, gHg, outp);
}

// Round 5
// 16.439 us; speedup vs baseline: 2.3486x; 2.3486x over previous
//
#include <hip/hip_runtime.h>
#include <hip/hip_bf16.h>

#define D 64      // hidden dim
#define D2 128    // ff inner dim
#define NV 64     // vocab size
#define NT 4      // num query types
#define NB 256    // batch
#define LL 4096   // seq len
#define KK 8      // memory slots

// ---------------------------------------------------------------------------
// Kernel 1: per-token-value precompute. grid = NV blocks, 256 threads.
// H[v] = LN(embed[v] + FFN(embed[v])); gH[v] = H[v].gate_w[:64];
// Qrow[v] = H[v] @ q_w + q_b.
// ALL weights are preloaded into registers before any compute, so the kernel
// has one global-latency wait instead of one per matvec phase.
// ---------------------------------------------------------------------------
__global__ void __launch_bounds__(256) precompute_kernel(
    const float* __restrict__ embed,
    const float* __restrict__ ff1_w, const float* __restrict__ ff1_b,
    const float* __restrict__ ff2_w, const float* __restrict__ ff2_b,
    const float* __restrict__ ln_g,  const float* __restrict__ ln_b,
    const float* __restrict__ gate_w,
    const float* __restrict__ q_w,   const float* __restrict__ q_b,
    float* __restrict__ Hout, float* __restrict__ gHout, float* __restrict__ Qout)
{
    __shared__ float sE[D];
    __shared__ float sP[256];
    __shared__ float sF[D2];
    __shared__ float sH[D];

    const int v   = blockIdx.x;
    const int tid = threadIdx.x;
    const int o1 = tid & (D2-1), h1 = tid >> 7;   // ff1 mapping: out o1, half h1
    const int o2 = tid & 63,     q2 = tid >> 6;   // ff2/q mapping: out o2, quarter q2

    // ---- issue ALL global loads up front (registers; static indices) -------
    float w1[32], w2[32], wq[16];
    #pragma unroll
    for (int k = 0; k < 32; ++k) w1[k] = ff1_w[(h1*32 + k)*D2 + o1];
    #pragma unroll
    for (int k = 0; k < 32; ++k) w2[k] = ff2_w[(q2*32 + k)*D + o2];
    #pragma unroll
    for (int k = 0; k < 16; ++k) wq[k] = q_w[(q2*16 + k)*D + o2];
    const float b1 = (tid < D2) ? ff1_b[tid] : 0.0f;
    float b2 = 0.f, lg = 0.f, lb = 0.f, gw = 0.f, qb = 0.f;
    if (tid < D) {
        b2 = ff2_b[tid]; lg = ln_g[tid]; lb = ln_b[tid];
        gw = gate_w[tid]; qb = q_b[tid];
        sE[tid] = embed[v*D + tid];
    }
    __syncthreads();   // one wait: everything above is now resident

    // ---- ff1 partials (out o1; half h1 covers 32 of 64 i's) ----------------
    {
        float acc = 0.0f;
        #pragma unroll
        for (int k = 0; k < 32; ++k) acc = fmaf(sE[h1*32 + k], w1[k], acc);
        sP[tid] = acc;
    }
    __syncthreads();
    if (tid < D2) sF[tid] = fmaxf(sP[tid] + sP[tid+128] + b1, 0.0f);
    __syncthreads();

    // ---- ff2 partials (out o2; quarter q2 covers 32 of 128 j's) ------------
    {
        float acc = 0.0f;
        #pragma unroll
        for (int k = 0; k < 32; ++k) acc = fmaf(sF[q2*32 + k], w2[k], acc);
        sP[tid] = acc;
    }
    __syncthreads();

    // ---- residual + LayerNorm on wave 0 ------------------------------------
    if (tid < D) {
        float x = sE[tid] + sP[tid] + sP[tid+64] + sP[tid+128] + sP[tid+192] + b2;
        float s = x;
        #pragma unroll
        for (int off = 32; off >= 1; off >>= 1) s += __shfl_xor(s, off, 64);
        const float mu = s * (1.0f / D);
        const float t  = x - mu;
        float vs = t * t;
        #pragma unroll
        for (int off = 32; off >= 1; off >>= 1) vs += __shfl_xor(vs, off, 64);
        const float rs = rsqrtf(vs * (1.0f / D) + 1e-5f);
        const float h  = t * rs * lg + lb;
        sH[tid] = h;
        Hout[v*D + tid] = h;
        float g = h * gw;
        #pragma unroll
        for (int off = 32; off >= 1; off >>= 1) g += __shfl_xor(g, off, 64);
        if (tid == 0) gHout[v] = g;
    }
    __syncthreads();

    // ---- Qrow partials (out o2; quarter q2 covers 16 of 64 i's) ------------
    {
        float acc = 0.0f;
        #pragma unroll
        for (int k = 0; k < 16; ++k) acc = fmaf(sH[q2*16 + k], wq[k], acc);
        sP[tid] = acc;
    }
    __syncthreads();
    if (tid < D)
        Qout[v*D + tid] = sP[tid] + sP[tid+64] + sP[tid+128] + sP[tid+192] + qb;
}

// ---------------------------------------------------------------------------
// Kernel 2: per-batch-row histogram + finalize. grid = NB blocks, 256 threads.
// Only the reused H table lives in LDS. out_w goes to 16 regs/thread (issued
// at t=0, consumed at the end); Q is read as ONE row (Q[slast]) issued right
// after seq lands and consumed several phases later.
// ---------------------------------------------------------------------------
__global__ void __launch_bounds__(256) batch_kernel(
    const int*   __restrict__ seq,
    const float* __restrict__ Hc, const float* __restrict__ gHc, const float* __restrict__ Qc,
    const float* __restrict__ tp_w, const float* __restrict__ tp_b,
    const float* __restrict__ out_w, const float* __restrict__ out_b,
    float* __restrict__ out)   // logits [0, NB*D), type_dist [NB*D, NB*D+NB*NT)
{
    __shared__ float sH[NV * D];     // 16 KB H table (reused by 4 phases)
    __shared__ float sP[256];
    __shared__ float stp[D * NT];
    __shared__ float sgv[NV];
    __shared__ float smean[D];
    __shared__ float sq[D];
    __shared__ float sread[D];
    __shared__ float std4[NT];
    __shared__ int   cnt[NV];
    __shared__ int   order[NV];
    __shared__ int   selv[KK], selc[KK];
    __shared__ float selw[KK], ssc[KK];
    __shared__ int   snsel, slastS;

    const int b   = blockIdx.x;
    const int tid = threadIdx.x;
    const int d   = tid & 63, g = tid >> 6;   // 4-way split mapping

    // ---- issue ALL independent global loads up front ------------------------
    const int4* s4 = reinterpret_cast<const int4*>(seq + (size_t)b * LL);
    const int4 x0 = s4[tid];
    const int4 x1 = s4[256 + tid];
    const int4 x2 = s4[512 + tid];
    const int4 x3 = s4[768 + tid];
    float wo[16];
    #pragma unroll
    for (int k = 0; k < 16; ++k) wo[k] = out_w[(g*16 + k)*D + d];
    {
        const float4* h4 = reinterpret_cast<const float4*>(Hc);
        float4* sh4 = reinterpret_cast<float4*>(sH);
        #pragma unroll
        for (int k = 0; k < 4; ++k) sh4[k*256 + tid] = h4[k*256 + tid];
    }
    stp[tid] = tp_w[tid];                               // D*NT == 256 exactly
    if (tid < NV) { cnt[tid] = 0; sgv[tid] = gHc[tid]; }
    const float oubr = (tid < D) ? out_b[tid] : 0.0f;
    if (tid == 255) slastS = x3.w;    // seq[b][4095], already in register
    __syncthreads();

    // ---- dependent Q-row load issued ASAP; consumed phases later -----------
    float qf = 0.0f;
    if (tid < D) qf = Qc[slastS*D + tid];

    // ---- histogram (16 LDS atomics/thread; overlaps qf latency) ------------
    atomicAdd(&cnt[x0.x], 1); atomicAdd(&cnt[x0.y], 1);
    atomicAdd(&cnt[x0.z], 1); atomicAdd(&cnt[x0.w], 1);
    atomicAdd(&cnt[x1.x], 1); atomicAdd(&cnt[x1.y], 1);
    atomicAdd(&cnt[x1.z], 1); atomicAdd(&cnt[x1.w], 1);
    atomicAdd(&cnt[x2.x], 1); atomicAdd(&cnt[x2.y], 1);
    atomicAdd(&cnt[x2.z], 1); atomicAdd(&cnt[x2.w], 1);
    atomicAdd(&cnt[x3.x], 1); atomicAdd(&cnt[x3.y], 1);
    atomicAdd(&cnt[x3.z], 1); atomicAdd(&cnt[x3.w], 1);
    __syncthreads();

    // ---- meanh[d] = sum_v cnt[v]*H[v][d] / L  (4-way split) ----------------
    {
        float acc = 0.0f;
        #pragma unroll
        for (int k = 0; k < 16; ++k) {
            const int v = g*16 + k;
            acc = fmaf((float)cnt[v], sH[v*D + d], acc);
        }
        sP[tid] = acc;
    }
    __syncthreads();
    if (tid < D)
        smean[tid] = (sP[tid] + sP[tid+64] + sP[tid+128] + sP[tid+192]) * (1.0f / LL);
    __syncthreads();

    // ---- type logits: wave g computes logit g (incl. bias) -----------------
    {
        float val = smean[d] * stp[d*NT + g];
        #pragma unroll
        for (int off = 32; off >= 1; off >>= 1) val += __shfl_xor(val, off, 64);
        if (d == 0) std4[g] = val + tp_b[g];   // scalar L2 hit, off critical path
    }
    __syncthreads();
    if (tid < NT) {
        const float a0 = std4[0], a1 = std4[1], a2 = std4[2], a3 = std4[3];
        const float mx = fmaxf(fmaxf(a0, a1), fmaxf(a2, a3));
        const float den = expf(a0-mx) + expf(a1-mx) + expf(a2-mx) + expf(a3-mx);
        out[NB*D + b*NT + tid] = expf(std4[tid] - mx) / den;
    }

    // ---- rank present token values by (gH desc, id asc) --------------------
    // sigmoid(gH + per-row-const) is strictly monotone in gH -> same top-k as
    // the reference; tpr/gate_b/sigmoid drop out. Same-id ties give identical
    // h rows; distinct-id exact-float ties are measure-zero.
    if (tid < NV && cnt[tid] > 0) {
        const float gv = sgv[tid];
        int r = 0;
        for (int u = 0; u < NV; ++u) {
            if (cnt[u] > 0) {
                const float gu = sgv[u];
                if (gu > gv || (gu == gv && u < tid)) ++r;
            }
        }
        order[r] = tid;
    }
    if (tid < D) sq[tid] = qf;        // q row to LDS (latency long gone)
    __syncthreads();

    // ---- top-8 multiset walk (<=8 steps) -----------------------------------
    if (tid == 0) {
        int taken = 0, idx = 0;
        while (taken < KK) {
            const int v = order[idx];
            int c = cnt[v]; if (c > KK - taken) c = KK - taken;
            selv[idx] = v; selc[idx] = c; taken += c; ++idx;
        }
        snsel = idx;
    }
    __syncthreads();

    // ---- attention scores: wave g handles slots g and g+4 ------------------
    {
        const int n = snsel;
        #pragma unroll
        for (int s = 0; s < KK; s += 4) {
            const int slot = s + g;
            if (slot < n) {
                float val = sH[selv[slot]*D + d] * sq[d];
                #pragma unroll
                for (int off = 32; off >= 1; off >>= 1) val += __shfl_xor(val, off, 64);
                if (d == 0) ssc[slot] = val;
            }
        }
    }
    __syncthreads();
    if (tid == 0) {
        const int n = snsel;
        float mx = -1e30f;
        for (int i = 0; i < n; ++i) mx = fmaxf(mx, ssc[i]);
        float e[KK]; float den = 0.0f;
        for (int i = 0; i < n; ++i) { e[i] = (float)selc[i] * expf(ssc[i] - mx); den += e[i]; }
        const float inv = 1.0f / den;
        for (int i = 0; i < n; ++i) selw[i] = e[i] * inv;
    }
    __syncthreads();

    // ---- read vector --------------------------------------------------------
    if (tid < D) {
        float acc = 0.0f;
        const int n = snsel;
        for (int s = 0; s < n; ++s) acc = fmaf(selw[s], sH[selv[s]*D + tid], acc);
        sread[tid] = acc;
    }
    __syncthreads();

    // ---- logits = read @ out_w + out_b (out_w already in registers) --------
    {
        float acc = 0.0f;
        #pragma unroll
        for (int k = 0; k < 16; ++k) acc = fmaf(sread[g*16 + k], wo[k], acc);
        sP[tid] = acc;
    }
    __syncthreads();
    if (tid < D)
        out[(size_t)b*D + tid] = sP[tid] + sP[tid+64] + sP[tid+128] + sP[tid+192] + oubr;
}

// ---------------------------------------------------------------------------
extern "C" void kernel_launch(void* const* d_in, const int* in_sizes, int n_in,
                              void* d_out, int out_size, void* d_ws, size_t ws_size,
                              hipStream_t stream) {
    const int*   seq    = (const int*)  d_in[0];
    const float* embed  = (const float*)d_in[1];
    const float* ff1_w  = (const float*)d_in[2];
    const float* ff1_b  = (const float*)d_in[3];
    const float* ff2_w  = (const float*)d_in[4];
    const float* ff2_b  = (const float*)d_in[5];
    const float* ln_g   = (const float*)d_in[6];
    const float* ln_b   = (const float*)d_in[7];
    const float* tp_w   = (const float*)d_in[8];
    const float* tp_b   = (const float*)d_in[9];
    // d_in[10] tpr_w, d_in[11] tpr_b, d_in[13] gate_b: dead — they only add a
    // per-row constant to the pre-sigmoid gate, which cannot change top-k.
    const float* gate_w = (const float*)d_in[12];
    const float* q_w    = (const float*)d_in[14];
    const float* q_b    = (const float*)d_in[15];
    const float* out_w  = (const float*)d_in[16];
    const float* out_b  = (const float*)d_in[17];
    float* outp = (float*)d_out;

    float* ws = (float*)d_ws;
    float* H  = ws;               // 4096 floats
    float* gH = ws + 4096;        // 64 floats
    float* Q  = ws + 4096 + 64;   // 4096 floats

    precompute_kernel<<<NV, 256, 0, stream>>>(embed, ff1_w, ff1_b, ff2_w, ff2_b,
                                              ln_g, ln_b, gate_w, q_w, q_b,
                                              H, gH, Q);
    batch_kernel<<<NB, 256, 0, stream>>>(seq, H, gH, Q, tp_w, tp_b,
                                         out_w, out_b, outp);
}